// Round 15
// baseline (141.702 us; speedup 1.0000x reference)
//
#include <hip/hip_runtime.h>
#include <stdint.h>

#define NFFT    1024
#define HOP     160
#define NMELS   160
#define SEG     32000
#define PADW    512
#define NFRAMES 201
#define NBATCH  256
#define NFREQ   256
#define FBW     12
#define NSTEP   32               // K-steps of 32
#define ROWB    336              // padded row bytes (160 samples + 8 pad)
#define NROWS   230              // rows per batch (frame 223 reads through row 229)
#define WPCH    (NROWS * 21)     // 4830 u4 chunks per batch
#define WPB2    (WPCH * 8)       // 38,640 halfwords per batch
#define LDSB    77312            // LDS bytes (>= NROWS*ROWB = 77,280)
#define PWSTR   456              // power tile col stride bytes (114 f32)

using bf16x8 = __attribute__((ext_vector_type(8))) __bf16;
using f32x4  = __attribute__((ext_vector_type(4))) float;

static __device__ __forceinline__ uint16_t f2bf(float f) {
    union { float f; uint32_t u; } v; v.f = f;
    return (uint16_t)((v.u + 0x7FFFu + ((v.u >> 16) & 1u)) >> 16);
}
static __device__ __forceinline__ void gload16(const void* g, void* l) {
    __builtin_amdgcn_global_load_lds(
        (const __attribute__((address_space(1))) uint32_t*)(uintptr_t)g,
        (__attribute__((address_space(3))) uint32_t*)(uintptr_t)l,
        16, 0, 0);
}

// ==== fused prep: pad(row-layout, 230 rows) | btf(frag-major) | fb | zero ====
#define PAD_BLKS  (NBATCH * 19)   // 4864 (19 x 256 covers 4830 chunks)
#define BTF_BLKS  256
#define ZERO_BLKS 1005            // 1005*256*8 float4 = 8,232,960 floats exact
#define PREP_GRID (PAD_BLKS + BTF_BLKS + 1 + ZERO_BLKS)

__global__ void k_prep(const float* __restrict__ wav, const float* __restrict__ win,
                       const float* __restrict__ dre, const float* __restrict__ dimg,
                       const float* __restrict__ mfb,
                       uint16_t* __restrict__ wp2, uint16_t* __restrict__ BTf,
                       int* __restrict__ klo, int* __restrict__ kw,
                       float* __restrict__ fbv, float* __restrict__ out) {
    int bid = blockIdx.x, tid = threadIdx.x;
    if (bid < PAD_BLKS) {
        int b = bid / 19, ib = bid - b * 19;
        int chunk = ib * 256 + tid;          // 0..4863
        if (chunk >= WPCH) return;
        int row = chunk / 21, cc = chunk - row * 21;
        uint16_t r[8] = {0,0,0,0,0,0,0,0};
        if (cc < 20) {                       // last chunk of each row = stride pad
            int s0 = row * 160 + cc * 8;     // padded-sample index
            if (s0 >= PADW && s0 + 8 <= PADW + SEG) {
                const float* s = wav + (size_t)b * SEG + (s0 - PADW);
                float4 v0 = *(const float4*)s;
                float4 v1 = *(const float4*)(s + 4);
                r[0]=f2bf(v0.x); r[1]=f2bf(v0.y); r[2]=f2bf(v0.z); r[3]=f2bf(v0.w);
                r[4]=f2bf(v1.x); r[5]=f2bf(v1.y); r[6]=f2bf(v1.z); r[7]=f2bf(v1.w);
            } else {
                #pragma unroll
                for (int e = 0; e < 8; ++e) {
                    int i = s0 + e - PADW;   // reflect; in-bounds for all rows<230
                    int j = (i < 0) ? -i : ((i >= SEG) ? (2 * SEG - 2 - i) : i);
                    r[e] = f2bf(wav[(size_t)b * SEG + j]);
                }
            }
        }
        *(uint4*)(wp2 + (size_t)b * WPB2 + (size_t)chunk * 8) = *(const uint4*)r;
    } else if (bid < PAD_BLKS + BTF_BLKS) {
        // BTf frag-major: flat ((vfrag*32 + kstep)*64 + lane)*8 halfwords,
        // vfrag = mat*16 + ntile; lane: l15 = bin%16, lg = k-chunk
        int idx8 = (bid - PAD_BLKS) * 256 + tid;
        int lane  = idx8 & 63;
        int kstep = (idx8 >> 6) & 31;
        int ntile = (idx8 >> 11) & 15;
        int mat   = idx8 >> 15;
        int bin = ntile * 16 + (lane & 15);
        int k0  = kstep * 32 + (lane >> 4) * 8;
        const float* src = (mat ? dimg : dre) + (size_t)bin * 1024 + k0;
        const float* w   = win + k0;
        uint16_t r[8];
        #pragma unroll
        for (int j = 0; j < 8; ++j) r[j] = f2bf(src[j] * w[j]);
        *(uint4*)(BTf + (size_t)idx8 * 8) = *(const uint4*)r;
    } else if (bid < PAD_BLKS + BTF_BLKS + 1) {
        int m = tid;
        if (m >= NMELS) return;
        int lo = -1, hi = -1;
        for (int f = 0; f < NFREQ; ++f) {
            float v = mfb[m * 513 + f];
            if (v > 0.f) { if (lo < 0) lo = f; hi = f; }
        }
        int w = (lo < 0) ? 0 : (hi - lo + 1);
        if (w > FBW) w = FBW;
        if (lo < 0) lo = 0;
        klo[m] = lo; kw[m] = w;
        for (int j = 0; j < w; ++j) fbv[m * FBW + j] = mfb[m * 513 + lo + j];
    } else {
        int sub = bid - (PAD_BLKS + BTF_BLKS + 1);
        float4* p = (float4*)out + ((size_t)sub * 256 + tid) * 8;
        #pragma unroll
        for (int j = 0; j < 8; ++j) p[j] = float4{0.f, 0.f, 0.f, 0.f};
    }
}

// ==== main: block = (batch, bin-half). 512 blocks, 8 waves = 2M x 4N.
// M = 224 rows (full batch, LDS-resident 77KB); N = 16 vfrags (8 ntiles x R,I).
// Wave (wm,wn): 7 M-frags (wm*112 rows) x {ntile wn*2, wn*2+1} x {R,I}.
// KEY: the two wm-waves with equal wn read IDENTICAL B bytes -> L1 reuse; block
// B-slice = 512KB (was 1MB) -> global B-traffic ~4x lower. Power = R^2+I^2 in
// REGISTERS (wave owns R and I of its bins). Barrier-free unrolled K-loop,
// cross-iter double-buffered operands, compile-time A offsets.
__global__ __launch_bounds__(512, 1) void k_main(
    const uint16_t* __restrict__ wp2, const uint16_t* __restrict__ BTf,
    const int* __restrict__ klo, const int* __restrict__ kw,
    const float* __restrict__ fbv, float* __restrict__ out)
{
    __shared__ uint4 smem4[LDSB / 16];
    char* smem = (char*)smem4;

    const int tid  = threadIdx.x;
    const int lane = tid & 63;
    const int wave = tid >> 6;
    const int wm = wave >> 2, wn = wave & 3;
    const int l15 = lane & 15, lg = lane >> 4;
    const int b = blockIdx.x;
    const int h = blockIdx.y;                // bin half: bins [h*128, h*128+128)

    // ---- fill LDS with all 230 rows (4830 chunks)
    const uint16_t* wsrc = wp2 + (size_t)b * WPB2;
    #pragma unroll
    for (int i = 0; i < 9; ++i)
        gload16(wsrc + (size_t)(tid + i * 512) * 8, smem + (size_t)(tid + i * 512) * 16);
    if (tid < WPCH - 4608)                   // 222 tail chunks
        gload16(wsrc + (size_t)(tid + 4608) * 8, smem + (size_t)(tid + 4608) * 16);
    asm volatile("s_waitcnt vmcnt(0)" ::: "memory");
    __syncthreads();

    // ---- A base: rows wm*112 + fi*16 + l15; B base: vfrags h*8 + wn*2 (+16 for I)
    const uint32_t alane = (uint32_t)((wm * 112 + l15) * ROWB + lg * 16);
    const uint16_t* bp = BTf + (size_t)(h * 8 + wn * 2) * 16384 + lane * 8;

    f32x4 acc[7][4];                         // nf: 0=R.nt0 1=R.nt1 2=I.nt0 3=I.nt1
    #pragma unroll
    for (int fi = 0; fi < 7; ++fi)
        #pragma unroll
        for (int nf = 0; nf < 4; ++nf)
            acc[fi][nf] = f32x4{0.f, 0.f, 0.f, 0.f};

    bf16x8 bv0[4], bv1[4], av0[7], av1[7];

    #define LOADB(dst, t) { \
        dst[0] = *(const bf16x8*)(bp + (size_t)(t) * 512); \
        dst[1] = *(const bf16x8*)(bp + 16384 + (size_t)(t) * 512); \
        dst[2] = *(const bf16x8*)(bp + 262144 + (size_t)(t) * 512); \
        dst[3] = *(const bf16x8*)(bp + 278528 + (size_t)(t) * 512); }
    #define LOADA(dst, t) { \
        const uint32_t aoff_ = (uint32_t)(((t) / 5) * ROWB + ((32 * (t)) % 160) * 2); \
        _Pragma("unroll") \
        for (int fi = 0; fi < 7; ++fi) \
            dst[fi] = *(const bf16x8*)(smem + alane + aoff_ + (uint32_t)(fi * 16 * ROWB)); }
    #define MFMA28(av, bv) { \
        __builtin_amdgcn_s_setprio(1); \
        _Pragma("unroll") \
        for (int fi = 0; fi < 7; ++fi) \
            _Pragma("unroll") \
            for (int nf = 0; nf < 4; ++nf) \
                acc[fi][nf] = __builtin_amdgcn_mfma_f32_16x16x32_bf16( \
                    av[fi], bv[nf], acc[fi][nf], 0, 0, 0); \
        __builtin_amdgcn_s_setprio(0); }

    LOADB(bv0, 0);
    LOADA(av0, 0);
    #pragma unroll
    for (int t = 0; t < NSTEP; ++t) {
        if (t & 1) {
            if (t + 1 < NSTEP) { LOADB(bv0, t + 1); LOADA(av0, t + 1); }
            MFMA28(av1, bv1);
        } else {
            if (t + 1 < NSTEP) { LOADB(bv1, t + 1); LOADA(av1, t + 1); }
            MFMA28(av0, bv0);
        }
    }
    __syncthreads();                         // waveform dead; overlay power tile

    // ---- epilogue: 2 passes of 112 rows. Power tile COL-MAJOR f32:
    // pw[col 0..127][row 0..111 (+2 pad)] at stride 456B -> mel reads are
    // frame-contiguous (lane=frame: conflict-free), mel index wave-uniform.
    char* pwb = smem;
    float* obase0 = out + (size_t)b * (NMELS * NFRAMES);
    const int nbase = h * 128;
    #pragma unroll
    for (int p = 0; p < 2; ++p) {
        if (wm == p) {
            #pragma unroll
            for (int fi = 0; fi < 7; ++fi)
                #pragma unroll
                for (int nt = 0; nt < 2; ++nt) {
                    f32x4 pv;
                    #pragma unroll
                    for (int e = 0; e < 4; ++e)
                        pv[e] = acc[fi][nt][e] * acc[fi][nt][e]
                              + acc[fi][nt + 2][e] * acc[fi][nt + 2][e];
                    const int col = (wn * 2 + nt) * 16 + l15;
                    *(f32x4*)(pwb + col * PWSTR + fi * 64 + lg * 16) = pv;
                }
        }
        __syncthreads();
        // mel projection: task = (mel m, frame-block); lane = frame within block
        for (int mt = wave; mt < NMELS * 2; mt += 8) {
            const int m = mt >> 1, fblk = mt & 1;
            const int f = fblk * 64 + lane;
            const int lo = klo[m], w = kw[m];
            int i0 = lo < nbase ? nbase : lo;
            int i1 = (lo + w < nbase + 128) ? (lo + w) : (nbase + 128);
            const int fg = p * 112 + f;
            if (i1 > i0 && f < 112 && fg <= 200) {
                float a = 0.f;
                for (int j = i0; j < i1; ++j)
                    a += fbv[m * FBW + (j - lo)] *
                         *(const float*)(pwb + (j - nbase) * PWSTR + f * 4);
                float* dst = obase0 + m * NFRAMES + fg;
                bool full = (lo >= nbase) && (lo + w <= nbase + 128);
                if (full) *dst = a;
                else      atomicAdd(dst, a);
            }
        }
        __syncthreads();
    }
}

extern "C" void kernel_launch(void* const* d_in, const int* in_sizes, int n_in,
                              void* d_out, int out_size, void* d_ws, size_t ws_size,
                              hipStream_t stream) {
    const float* wav  = (const float*)d_in[0];
    const float* win  = (const float*)d_in[1];
    const float* dre  = (const float*)d_in[2];
    const float* dimg = (const float*)d_in[3];
    const float* mfb  = (const float*)d_in[4];
    float* out = (float*)d_out;

    uint8_t* ws = (uint8_t*)d_ws;
    uint16_t* BTf = (uint16_t*)ws;                           // 1 MB frag-major DFT
    uint16_t* wp2 = (uint16_t*)(ws + (1u << 20));            // 19.8 MB row-padded wave
    size_t off = (1u << 20) + (size_t)NBATCH * WPB2 * 2;     // 20,832,256
    int*   klo = (int*)(ws + off);
    int*   kw  = (int*)(ws + off + 640);
    float* fbv = (float*)(ws + off + 1280);

    hipLaunchKernelGGL(k_prep, dim3(PREP_GRID), dim3(256), 0, stream,
                       wav, win, dre, dimg, mfb, wp2, BTf, klo, kw, fbv, out);
    hipLaunchKernelGGL(k_main, dim3(NBATCH, 2), dim3(512), 0, stream,
                       wp2, BTf, klo, kw, fbv, out);
}

// Round 16
// 119.154 us; speedup vs baseline: 1.1892x; 1.1892x over previous
//
#include <hip/hip_runtime.h>
#include <stdint.h>

#define NFFT    1024
#define HOP     160
#define NMELS   160
#define SEG     32000
#define PADW    512
#define NFRAMES 201
#define NBATCH  256
#define NFREQ   256
#define FBW     12
#define NSTEP   32               // K-steps of 32
#define ROWB    336              // padded row bytes (160 samples + 8 pad)
#define NROWS   230              // rows per batch (frame 223 reads through row 229)
#define WPCH    (NROWS * 21)     // 4830 u4 chunks per batch
#define WPB2    (WPCH * 8)       // 38,640 halfwords per batch
// LDS map (bytes):
//   [0, 77280)        waveform rows (230 x 336B)
//   [77312, 77952)    klo_lds[160]
//   [77952, 78592)    kw_lds[160]
//   [78592, 86272)    fbv_lds[160][12] f32
//   [86272, 144640)   pw: 128 cols x 114 f32 (456B col stride)
#define KLO_OFF   77312
#define KW_OFF    77952
#define FBV_OFF   78592
#define PW_OFF    86272
#define LDS_TOTAL 144640
#define PWSTR     114            // f32 per power col (112 rows + 2 pad)

using bf16x8 = __attribute__((ext_vector_type(8))) __bf16;
using f32x4  = __attribute__((ext_vector_type(4))) float;

static __device__ __forceinline__ uint16_t f2bf(float f) {
    union { float f; uint32_t u; } v; v.f = f;
    return (uint16_t)((v.u + 0x7FFFu + ((v.u >> 16) & 1u)) >> 16);
}
static __device__ __forceinline__ void gload16(const void* g, void* l) {
    __builtin_amdgcn_global_load_lds(
        (const __attribute__((address_space(1))) uint32_t*)(uintptr_t)g,
        (__attribute__((address_space(3))) uint32_t*)(uintptr_t)l,
        16, 0, 0);
}

// ==== fused prep: pad(row-layout, 230 rows) | btf(frag-major) | fb | zero ====
#define PAD_BLKS  (NBATCH * 19)   // 4864
#define BTF_BLKS  256
#define ZERO_BLKS 1005            // 1005*256*8 float4 = 8,232,960 floats exact
#define PREP_GRID (PAD_BLKS + BTF_BLKS + 1 + ZERO_BLKS)

__global__ void k_prep(const float* __restrict__ wav, const float* __restrict__ win,
                       const float* __restrict__ dre, const float* __restrict__ dimg,
                       const float* __restrict__ mfb,
                       uint16_t* __restrict__ wp2, uint16_t* __restrict__ BTf,
                       int* __restrict__ klo, int* __restrict__ kw,
                       float* __restrict__ fbv, float* __restrict__ out) {
    int bid = blockIdx.x, tid = threadIdx.x;
    if (bid < PAD_BLKS) {
        int b = bid / 19, ib = bid - b * 19;
        int chunk = ib * 256 + tid;          // 0..4863
        if (chunk >= WPCH) return;
        int row = chunk / 21, cc = chunk - row * 21;
        uint16_t r[8] = {0,0,0,0,0,0,0,0};
        if (cc < 20) {
            int s0 = row * 160 + cc * 8;
            if (s0 >= PADW && s0 + 8 <= PADW + SEG) {
                const float* s = wav + (size_t)b * SEG + (s0 - PADW);
                float4 v0 = *(const float4*)s;
                float4 v1 = *(const float4*)(s + 4);
                r[0]=f2bf(v0.x); r[1]=f2bf(v0.y); r[2]=f2bf(v0.z); r[3]=f2bf(v0.w);
                r[4]=f2bf(v1.x); r[5]=f2bf(v1.y); r[6]=f2bf(v1.z); r[7]=f2bf(v1.w);
            } else {
                #pragma unroll
                for (int e = 0; e < 8; ++e) {
                    int i = s0 + e - PADW;
                    int j = (i < 0) ? -i : ((i >= SEG) ? (2 * SEG - 2 - i) : i);
                    r[e] = f2bf(wav[(size_t)b * SEG + j]);
                }
            }
        }
        *(uint4*)(wp2 + (size_t)b * WPB2 + (size_t)chunk * 8) = *(const uint4*)r;
    } else if (bid < PAD_BLKS + BTF_BLKS) {
        int idx8 = (bid - PAD_BLKS) * 256 + tid;
        int lane  = idx8 & 63;
        int kstep = (idx8 >> 6) & 31;
        int ntile = (idx8 >> 11) & 15;
        int mat   = idx8 >> 15;
        int bin = ntile * 16 + (lane & 15);
        int k0  = kstep * 32 + (lane >> 4) * 8;
        const float* src = (mat ? dimg : dre) + (size_t)bin * 1024 + k0;
        const float* w   = win + k0;
        uint16_t r[8];
        #pragma unroll
        for (int j = 0; j < 8; ++j) r[j] = f2bf(src[j] * w[j]);
        *(uint4*)(BTf + (size_t)idx8 * 8) = *(const uint4*)r;
    } else if (bid < PAD_BLKS + BTF_BLKS + 1) {
        int m = tid;
        if (m >= NMELS) return;
        int lo = -1, hi = -1;
        for (int f = 0; f < NFREQ; ++f) {
            float v = mfb[m * 513 + f];
            if (v > 0.f) { if (lo < 0) lo = f; hi = f; }
        }
        int w = (lo < 0) ? 0 : (hi - lo + 1);
        if (w > FBW) w = FBW;
        if (lo < 0) lo = 0;
        klo[m] = lo; kw[m] = w;
        for (int j = 0; j < w; ++j) fbv[m * FBW + j] = mfb[m * 513 + lo + j];
    } else {
        int sub = bid - (PAD_BLKS + BTF_BLKS + 1);
        float4* p = (float4*)out + ((size_t)sub * 256 + tid) * 8;
        #pragma unroll
        for (int j = 0; j < 8; ++j) p[j] = float4{0.f, 0.f, 0.f, 0.f};
    }
}

// ==== main: block = (batch, bin-half). 512 blocks, 8 waves = 2M x 4N.
// R16: (1) NO setprio in K-loop (2 waves/SIMD: prio-wrapping the MFMA cluster
// starves the sibling's load issue); (2) B prefetched TWO steps deep (bv
// 3-ring, static indices under full unroll) - drains loads issued ~2 clusters
// (~1100+cy) ago; av single-buffered (sibling's cluster covers ~120cy LDS lat);
// (3) epilogue reads klo/kw/fbv from LDS (broadcast) and power tile lives in
// its own LDS region (144.6KB total of 160KB).
__global__ __launch_bounds__(512, 1) void k_main(
    const uint16_t* __restrict__ wp2, const uint16_t* __restrict__ BTf,
    const int* __restrict__ klo, const int* __restrict__ kw,
    const float* __restrict__ fbv, float* __restrict__ out)
{
    __shared__ uint4 smem4[LDS_TOTAL / 16];
    char* smem = (char*)smem4;

    const int tid  = threadIdx.x;
    const int lane = tid & 63;
    const int wave = tid >> 6;
    const int wm = wave >> 2, wn = wave & 3;
    const int l15 = lane & 15, lg = lane >> 4;
    const int b = blockIdx.x;
    const int h = blockIdx.y;                // bin half: bins [h*128, h*128+128)

    // ---- fill LDS: waveform (4830 chunks) + fb tables
    const uint16_t* wsrc = wp2 + (size_t)b * WPB2;
    #pragma unroll
    for (int i = 0; i < 9; ++i)
        gload16(wsrc + (size_t)(tid + i * 512) * 8, smem + (size_t)(tid + i * 512) * 16);
    if (tid < WPCH - 4608)
        gload16(wsrc + (size_t)(tid + 4608) * 8, smem + (size_t)(tid + 4608) * 16);
    if (tid < NMELS) {
        *(int*)(smem + KLO_OFF + tid * 4) = klo[tid];
        *(int*)(smem + KW_OFF  + tid * 4) = kw[tid];
    }
    for (int i = tid; i < NMELS * FBW; i += 512)
        *(float*)(smem + FBV_OFF + i * 4) = fbv[i];
    asm volatile("s_waitcnt vmcnt(0)" ::: "memory");
    __syncthreads();

    // ---- A base: rows wm*112 + fi*16 + l15; B: vfrags h*8 + wn*2 (+16 for I)
    const uint32_t alane = (uint32_t)((wm * 112 + l15) * ROWB + lg * 16);
    const uint16_t* bp = BTf + (size_t)(h * 8 + wn * 2) * 16384 + lane * 8;

    f32x4 acc[7][4];                         // nf: 0=R.nt0 1=R.nt1 2=I.nt0 3=I.nt1
    #pragma unroll
    for (int fi = 0; fi < 7; ++fi)
        #pragma unroll
        for (int nf = 0; nf < 4; ++nf)
            acc[fi][nf] = f32x4{0.f, 0.f, 0.f, 0.f};

    bf16x8 bvA[4], bvB[4], bvC[4], av[7];

    #define LOADB(dst, t) { \
        dst[0] = *(const bf16x8*)(bp + (size_t)(t) * 512); \
        dst[1] = *(const bf16x8*)(bp + 16384 + (size_t)(t) * 512); \
        dst[2] = *(const bf16x8*)(bp + 262144 + (size_t)(t) * 512); \
        dst[3] = *(const bf16x8*)(bp + 278528 + (size_t)(t) * 512); }
    #define LOADA(t) { \
        const uint32_t aoff_ = (uint32_t)(((t) / 5) * ROWB + ((32 * (t)) % 160) * 2); \
        _Pragma("unroll") \
        for (int fi = 0; fi < 7; ++fi) \
            av[fi] = *(const bf16x8*)(smem + alane + aoff_ + (uint32_t)(fi * 16 * ROWB)); }
    #define MFMA28(bv) { \
        _Pragma("unroll") \
        for (int fi = 0; fi < 7; ++fi) \
            _Pragma("unroll") \
            for (int nf = 0; nf < 4; ++nf) \
                acc[fi][nf] = __builtin_amdgcn_mfma_f32_16x16x32_bf16( \
                    av[fi], bv[nf], acc[fi][nf], 0, 0, 0); }

    LOADB(bvA, 0);
    LOADB(bvB, 1);
    #pragma unroll
    for (int t = 0; t < NSTEP; ++t) {
        LOADA(t);                            // this-step A (7 ds_read_b128)
        if (t + 2 < NSTEP) {                 // 2-deep B prefetch into ring slot
            const int n2 = (t + 2) % 3;
            if      (n2 == 0) { LOADB(bvA, t + 2); }
            else if (n2 == 1) { LOADB(bvB, t + 2); }
            else              { LOADB(bvC, t + 2); }
        }
        const int c = t % 3;
        if      (c == 0) { MFMA28(bvA); }
        else if (c == 1) { MFMA28(bvB); }
        else             { MFMA28(bvC); }
    }
    __syncthreads();

    // ---- epilogue: 2 passes of 112 rows; power tile col-major f32 in own region
    float* pwf = (float*)(smem + PW_OFF);
    const int* klo_l = (const int*)(smem + KLO_OFF);
    const int* kw_l  = (const int*)(smem + KW_OFF);
    const float* fbv_l = (const float*)(smem + FBV_OFF);
    float* obase0 = out + (size_t)b * (NMELS * NFRAMES);
    const int nbase = h * 128;
    #pragma unroll
    for (int p = 0; p < 2; ++p) {
        if (wm == p) {
            #pragma unroll
            for (int fi = 0; fi < 7; ++fi)
                #pragma unroll
                for (int nt = 0; nt < 2; ++nt) {
                    f32x4 pv;
                    #pragma unroll
                    for (int e = 0; e < 4; ++e)
                        pv[e] = acc[fi][nt][e] * acc[fi][nt][e]
                              + acc[fi][nt + 2][e] * acc[fi][nt + 2][e];
                    const int col = (wn * 2 + nt) * 16 + l15;
                    *(f32x4*)(pwf + col * PWSTR + fi * 16 + lg * 4) = pv;
                }
        }
        __syncthreads();
        // mel projection: lane = frame; klo/kw/fbv broadcast from LDS
        for (int mt = wave; mt < NMELS * 2; mt += 8) {
            const int m = mt >> 1, fblk = mt & 1;
            const int f = fblk * 64 + lane;
            const int lo = klo_l[m], w = kw_l[m];
            int i0 = lo < nbase ? nbase : lo;
            int i1 = (lo + w < nbase + 128) ? (lo + w) : (nbase + 128);
            const int fg = p * 112 + f;
            if (i1 > i0 && f < 112 && fg <= 200) {
                float a = 0.f;
                for (int j = i0; j < i1; ++j)
                    a += fbv_l[m * FBW + (j - lo)] * pwf[(j - nbase) * PWSTR + f];
                float* dst = obase0 + m * NFRAMES + fg;
                bool full = (lo >= nbase) && (lo + w <= nbase + 128);
                if (full) *dst = a;
                else      atomicAdd(dst, a);
            }
        }
        __syncthreads();
    }
}

extern "C" void kernel_launch(void* const* d_in, const int* in_sizes, int n_in,
                              void* d_out, int out_size, void* d_ws, size_t ws_size,
                              hipStream_t stream) {
    const float* wav  = (const float*)d_in[0];
    const float* win  = (const float*)d_in[1];
    const float* dre  = (const float*)d_in[2];
    const float* dimg = (const float*)d_in[3];
    const float* mfb  = (const float*)d_in[4];
    float* out = (float*)d_out;

    uint8_t* ws = (uint8_t*)d_ws;
    uint16_t* BTf = (uint16_t*)ws;                           // 1 MB frag-major DFT
    uint16_t* wp2 = (uint16_t*)(ws + (1u << 20));            // 19.8 MB row-padded wave
    size_t off = (1u << 20) + (size_t)NBATCH * WPB2 * 2;
    int*   klo = (int*)(ws + off);
    int*   kw  = (int*)(ws + off + 640);
    float* fbv = (float*)(ws + off + 1280);

    hipLaunchKernelGGL(k_prep, dim3(PREP_GRID), dim3(256), 0, stream,
                       wav, win, dre, dimg, mfb, wp2, BTf, klo, kw, fbv, out);
    hipLaunchKernelGGL(k_main, dim3(NBATCH, 2), dim3(512), 0, stream,
                       wp2, BTf, klo, kw, fbv, out);
}

// Round 17
// 80.062 us; speedup vs baseline: 1.7699x; 1.4883x over previous
//
#include <hip/hip_runtime.h>
#include <stdint.h>

#define NFFT    1024
#define HOP     160
#define NMELS   160
#define SEG     32000
#define PADW    512
#define NFRAMES 201
#define NBATCH  256
#define FBW     12
#define NSTEP   32               // K-steps of 32
#define ROWB    336              // padded row bytes (160 samples + 8 pad)
#define NROWS   230
#define WPCH    (NROWS * 21)     // 4830 u4 chunks per batch
#define WPB2    (WPCH * 8)       // 38,640 halfwords per batch
#define FILLCH  2496             // chunks per half fill (118 rows + align)

using bf16x8 = __attribute__((ext_vector_type(8))) __bf16;
using f32x4  = __attribute__((ext_vector_type(4))) float;

static __device__ __forceinline__ uint16_t f2bf(float f) {
    union { float f; uint32_t u; } v; v.f = f;
    return (uint16_t)((v.u + 0x7FFFu + ((v.u >> 16) & 1u)) >> 16);
}
static __device__ __forceinline__ void gload16(const void* g, void* l) {
    __builtin_amdgcn_global_load_lds(
        (const __attribute__((address_space(1))) uint32_t*)(uintptr_t)g,
        (__attribute__((address_space(3))) uint32_t*)(uintptr_t)l,
        16, 0, 0);
}

// ==== fused prep: pad(row-layout) | btf(frag-major) | fbT(frag-major dense) ====
#define PAD_BLKS  (NBATCH * 19)   // 4864
#define BTF_BLKS  256
#define FBT_BLKS  20              // 5120 threads: 80 frags x 64 lanes
#define PREP_GRID (PAD_BLKS + BTF_BLKS + FBT_BLKS)

__global__ void k_prep(const float* __restrict__ wav, const float* __restrict__ win,
                       const float* __restrict__ dre, const float* __restrict__ dimg,
                       const float* __restrict__ mfb,
                       uint16_t* __restrict__ wp2, uint16_t* __restrict__ BTf,
                       uint16_t* __restrict__ fbT) {
    int bid = blockIdx.x, tid = threadIdx.x;
    if (bid < PAD_BLKS) {
        int b = bid / 19, ib = bid - b * 19;
        int chunk = ib * 256 + tid;
        if (chunk >= WPCH) return;
        int row = chunk / 21, cc = chunk - row * 21;
        uint16_t r[8] = {0,0,0,0,0,0,0,0};
        if (cc < 20) {
            int s0 = row * 160 + cc * 8;
            if (s0 >= PADW && s0 + 8 <= PADW + SEG) {
                const float* s = wav + (size_t)b * SEG + (s0 - PADW);
                float4 v0 = *(const float4*)s;
                float4 v1 = *(const float4*)(s + 4);
                r[0]=f2bf(v0.x); r[1]=f2bf(v0.y); r[2]=f2bf(v0.z); r[3]=f2bf(v0.w);
                r[4]=f2bf(v1.x); r[5]=f2bf(v1.y); r[6]=f2bf(v1.z); r[7]=f2bf(v1.w);
            } else {
                #pragma unroll
                for (int e = 0; e < 8; ++e) {
                    int i = s0 + e - PADW;
                    int j = (i < 0) ? -i : ((i >= SEG) ? (2 * SEG - 2 - i) : i);
                    r[e] = f2bf(wav[(size_t)b * SEG + j]);
                }
            }
        }
        *(uint4*)(wp2 + (size_t)b * WPB2 + (size_t)chunk * 8) = *(const uint4*)r;
    } else if (bid < PAD_BLKS + BTF_BLKS) {
        // BTf frag-major: ((vfrag*32 + kstep)*64 + lane)*8; vfrag = mat*16+ntile
        int idx8 = (bid - PAD_BLKS) * 256 + tid;
        int lane  = idx8 & 63;
        int kstep = (idx8 >> 6) & 31;
        int ntile = (idx8 >> 11) & 15;
        int mat   = idx8 >> 15;
        int bin = ntile * 16 + (lane & 15);
        int k0  = kstep * 32 + (lane >> 4) * 8;
        const float* src = (mat ? dimg : dre) + (size_t)bin * 1024 + k0;
        const float* w   = win + k0;
        uint16_t r[8];
        #pragma unroll
        for (int j = 0; j < 8; ++j) r[j] = f2bf(src[j] * w[j]);
        *(uint4*)(BTf + (size_t)idx8 * 8) = *(const uint4*)r;
    } else {
        // fbT frag-major dense: ((mt*8 + kf)*64 + lane)*8; mel = mt*16+l15,
        // bins kf*32 + lg*8 + j (bins >= 256 never exist here; mfb cols < 513)
        int idx = (bid - PAD_BLKS - BTF_BLKS) * 256 + tid;   // 0..5119
        if (idx >= 5120) return;
        int lane = idx & 63;
        int fI = idx >> 6;                    // 0..79
        int kf = fI & 7, mt = fI >> 3;
        int mel = mt * 16 + (lane & 15);
        int b0  = kf * 32 + (lane >> 4) * 8;
        const float* s = mfb + (size_t)mel * 513 + b0;
        uint16_t r[8];
        #pragma unroll
        for (int j = 0; j < 8; ++j) r[j] = f2bf(s[j]);
        *(uint4*)(fbT + (size_t)idx * 8) = *(const uint4*)r;
    }
}

// ==== main: block = (batch, frame-half). 512 blocks, 8 waves, 1M x 8N.
// Wave wn owns ALL 7 M-frags (112 frames) x vfrags {2wn,2wn+1,16+2wn,16+2wn+1}
// (R pair + I pair of bins wn*32..wn*32+31) -> power in registers, full K=256
// per block -> no atomics. K-loop: R16-proven (no setprio, 3-ring 2-deep B
// prefetch, single-buffer A ds_reads, barrier-free, fully unrolled).
// Epilogue: mel projection as MFMA GEMM out[m][f] = sum_k fb[m][k] pw[f][k]:
// pw[112][256] bf16 in LDS (rotation swizzle slot=(chunk+frame)&31, conflict-
// free b128 reads), fb from dense frag-major fbT (global, L2-hot). 560 MFMAs
// replace ~40us of latency-bound scalar LDS chains. Predicated coalesced store.
__global__ __launch_bounds__(512, 1) void k_main(
    const uint16_t* __restrict__ wp2, const uint16_t* __restrict__ BTf,
    const uint16_t* __restrict__ fbT, float* __restrict__ out)
{
    __shared__ uint4 smem4[57344 / 16];      // waveform [0,39936) / pw overlay
    char* smem = (char*)smem4;

    const int tid  = threadIdx.x;
    const int lane = tid & 63;
    const int wn   = tid >> 6;               // wave = N-slice
    const int l15 = lane & 15, lg = lane >> 4;
    const int b    = blockIdx.x;
    const int h    = blockIdx.y;
    const int r0   = h ? 96 : 0;             // first frame row of this half

    // ---- fill LDS rows r0..r0+117
    const uint16_t* wsrc = wp2 + (size_t)b * WPB2 + (size_t)r0 * 168;
    #pragma unroll
    for (int i = 0; i < 4; ++i)
        gload16(wsrc + (size_t)(tid + i * 512) * 8, smem + (size_t)(tid + i * 512) * 16);
    if (tid < FILLCH - 2048)                 // 448
        gload16(wsrc + (size_t)(tid + 2048) * 8, smem + (size_t)(tid + 2048) * 16);
    asm volatile("s_waitcnt vmcnt(0)" ::: "memory");
    __syncthreads();

    const uint32_t alane = (uint32_t)(l15 * ROWB + lg * 16);
    const uint16_t* bp = BTf + (size_t)(wn * 2) * 16384 + lane * 8;

    f32x4 acc[7][4];                         // nf: 0=R.nt0 1=R.nt1 2=I.nt0 3=I.nt1
    #pragma unroll
    for (int fi = 0; fi < 7; ++fi)
        #pragma unroll
        for (int nf = 0; nf < 4; ++nf)
            acc[fi][nf] = f32x4{0.f, 0.f, 0.f, 0.f};

    bf16x8 bvA[4], bvB[4], bvC[4], av[7];

    #define LOADB(dst, t) { \
        dst[0] = *(const bf16x8*)(bp + (size_t)(t) * 512); \
        dst[1] = *(const bf16x8*)(bp + 16384 + (size_t)(t) * 512); \
        dst[2] = *(const bf16x8*)(bp + 262144 + (size_t)(t) * 512); \
        dst[3] = *(const bf16x8*)(bp + 278528 + (size_t)(t) * 512); }
    #define LOADA(t) { \
        const uint32_t aoff_ = (uint32_t)(((t) / 5) * ROWB + ((32 * (t)) % 160) * 2); \
        _Pragma("unroll") \
        for (int fi = 0; fi < 7; ++fi) \
            av[fi] = *(const bf16x8*)(smem + alane + aoff_ + (uint32_t)(fi * 16 * ROWB)); }
    #define MFMA28(bv) { \
        _Pragma("unroll") \
        for (int fi = 0; fi < 7; ++fi) \
            _Pragma("unroll") \
            for (int nf = 0; nf < 4; ++nf) \
                acc[fi][nf] = __builtin_amdgcn_mfma_f32_16x16x32_bf16( \
                    av[fi], bv[nf], acc[fi][nf], 0, 0, 0); }

    LOADB(bvA, 0);
    LOADB(bvB, 1);
    #pragma unroll
    for (int t = 0; t < NSTEP; ++t) {
        LOADA(t);
        if (t + 2 < NSTEP) {
            const int n2 = (t + 2) % 3;
            if      (n2 == 0) { LOADB(bvA, t + 2); }
            else if (n2 == 1) { LOADB(bvB, t + 2); }
            else              { LOADB(bvC, t + 2); }
        }
        const int c = t % 3;
        if      (c == 0) { MFMA28(bvA); }
        else if (c == 1) { MFMA28(bvB); }
        else             { MFMA28(bvC); }
    }
    __syncthreads();                         // waveform dead

    // ---- power -> pw[112][256] bf16, rotation-swizzled 16B slots
    uint16_t* pw16 = (uint16_t*)smem;
    #pragma unroll
    for (int fi = 0; fi < 7; ++fi)
        #pragma unroll
        for (int nt = 0; nt < 2; ++nt)
            #pragma unroll
            for (int e = 0; e < 4; ++e) {
                const int frow = fi * 16 + lg * 4 + e;
                const int bin  = (wn * 2 + nt) * 16 + l15;
                float r = acc[fi][nt][e], im = acc[fi][nt + 2][e];
                const int slot = ((bin >> 3) + frow) & 31;
                *(uint16_t*)(smem + frow * 512 + slot * 16 + (bin & 7) * 2)
                    = f2bf(r * r + im * im);
            }
    __syncthreads();

    // ---- mel GEMM: 10 mtiles x 7 ftiles x 8 kfrags; round-robin tasks
    float* obase = out + (size_t)b * (NMELS * NFRAMES);
    for (int task = wn; task < 70; task += 8) {
        const int mt = task / 7, ft = task - mt * 7;
        f32x4 d = f32x4{0.f, 0.f, 0.f, 0.f};
        const int frame = ft * 16 + l15;
        #pragma unroll
        for (int kf = 0; kf < 8; ++kf) {
            bf16x8 a = *(const bf16x8*)(fbT + (size_t)((mt * 8 + kf) * 64 + lane) * 8);
            const int slot = (kf * 4 + lg + frame) & 31;
            bf16x8 bb = *(const bf16x8*)(smem + frame * 512 + slot * 16);
            d = __builtin_amdgcn_mfma_f32_16x16x32_bf16(a, bb, d, 0, 0, 0);
        }
        const int fg = r0 + frame;
        const bool own = h ? (fg >= 104 && fg <= 200) : (fg <= 103);
        if (own) {
            #pragma unroll
            for (int e = 0; e < 4; ++e)
                obase[(mt * 16 + lg * 4 + e) * NFRAMES + fg] = d[e];
        }
    }
}

extern "C" void kernel_launch(void* const* d_in, const int* in_sizes, int n_in,
                              void* d_out, int out_size, void* d_ws, size_t ws_size,
                              hipStream_t stream) {
    const float* wav  = (const float*)d_in[0];
    const float* win  = (const float*)d_in[1];
    const float* dre  = (const float*)d_in[2];
    const float* dimg = (const float*)d_in[3];
    const float* mfb  = (const float*)d_in[4];
    float* out = (float*)d_out;

    uint8_t* ws = (uint8_t*)d_ws;
    uint16_t* BTf = (uint16_t*)ws;                           // 1 MB frag-major DFT
    uint16_t* wp2 = (uint16_t*)(ws + (1u << 20));            // 19.8 MB padded wave
    size_t off = (1u << 20) + (size_t)NBATCH * WPB2 * 2;     // 20,832,256
    uint16_t* fbT = (uint16_t*)(ws + off);                   // 80 KB frag-major mel fb

    hipLaunchKernelGGL(k_prep, dim3(PREP_GRID), dim3(256), 0, stream,
                       wav, win, dre, dimg, mfb, wp2, BTf, fbT);
    hipLaunchKernelGGL(k_main, dim3(NBATCH, 2), dim3(512), 0, stream,
                       wp2, BTf, fbT, out);
}